// Round 5
// baseline (98.974 us; speedup 1.0000x reference)
//
#include <hip/hip_runtime.h>

// Problem constants: B=4, D=64, K=32, N = T*H*W = 8192
#define BB 4
#define DD 64
#define KK 32
#define NN 8192
#define LOG2E 1.4426950408889634f

typedef float f2 __attribute__((ext_vector_type(2)));

static __device__ __forceinline__ f2 pk_fma(f2 a, f2 b, f2 c) {
    return __builtin_elementwise_fma(a, b, c);   // -> v_pk_fma_f32
}

// Kernel 1: per (b,d) column chunk of 1024 n's (4/thread as 2x float2).
// E[b,d,n] = x - (sum_k e_k c_k)/(sum_k e_k), e_k = exp2(a x^2 + b x + c)
// with (a,b,c) wave-uniform per k (scale<0 -> args<=0, single-pass exp safe).
// Packed fp32 (v_pk_fma_f32) halves VALU issue slots; exp2 stays on the
// trans pipe. Block-reduces sum_n E into partial[blockIdx] (private slot).
__global__ __launch_bounds__(256) void enc_kernel(
    const float* __restrict__ X,        // [B, D, N]
    const float* __restrict__ cw,       // [K, D]
    const float* __restrict__ sc,       // [K, D]
    float* __restrict__ E,              // [B, D, N]  (= d_out, staging)
    float* __restrict__ partial)        // [2048] per-block sums
{
    const int bd   = blockIdx.x >> 3;         // (b,d) pair; 8 chunks each
    const int d    = bd & (DD - 1);
    const int idx  = bd * NN + (blockIdx.x & 7) * 1024 + (threadIdx.x << 2);

    const float4 x = *(const float4*)(X + idx);
    const f2 x01 = {x.x, x.y};
    const f2 x23 = {x.z, x.w};

    f2 den01 = {0.f, 0.f}, den23 = {0.f, 0.f};
    f2 cn01  = {0.f, 0.f}, cn23  = {0.f, 0.f};

#pragma unroll
    for (int k = 0; k < KK; ++k) {
        const float c  = cw[k * DD + d];              // wave-uniform -> s_load
        const float a  = sc[k * DD + d] * LOG2E;      // exp(x)=exp2(x*log2e)
        const float b2 = -2.0f * a * c;
        const float c2 = a * c * c;
        const f2 av = {a, a}, bv = {b2, b2}, cv = {c2, c2}, cb = {c, c};

        const f2 t01 = pk_fma(pk_fma(av, x01, bv), x01, cv);
        const f2 t23 = pk_fma(pk_fma(av, x23, bv), x23, cv);
        const f2 e01 = {exp2f(t01.x), exp2f(t01.y)};  // native v_exp_f32
        const f2 e23 = {exp2f(t23.x), exp2f(t23.y)};
        den01 += e01;                                  // v_pk_add_f32
        den23 += e23;
        cn01 = pk_fma(e01, cb, cn01);
        cn23 = pk_fma(e23, cb, cn23);
    }

    float4 out;
    out.x = x01.x - cn01.x / den01.x;   // = sum_k softmax_k * (x - c_k)
    out.y = x01.y - cn01.y / den01.y;
    out.z = x23.x - cn23.x / den23.x;
    out.w = x23.y - cn23.y / den23.y;
    *(float4*)(E + idx) = out;

    // block-reduce sum_n E -> private partial slot (no atomics, no memset)
    float t = out.x + out.y + out.z + out.w;
#pragma unroll
    for (int off = 32; off > 0; off >>= 1)
        t += __shfl_down(t, off);                     // wave = 64

    __shared__ float smem[4];
    if ((threadIdx.x & 63) == 0) smem[threadIdx.x >> 6] = t;
    __syncthreads();
    if (threadIdx.x == 0)
        partial[blockIdx.x] = smem[0] + smem[1] + smem[2] + smem[3];
}

// Kernel 2: reduce the 512 partials of batch b -> eglob[b,:], compute
// gamma(b,d) redundantly per block (64 FMAs), apply relu(E*(1+gamma)) in
// place. E is L2-resident from kernel 1 (same grid shape -> same XCD map).
__global__ __launch_bounds__(256) void gate_kernel(
    float* __restrict__ E,              // [B, D, N] in/out (= d_out)
    const float* __restrict__ partial,  // [2048]: partial[(b*64+j)*8 + c]
    const float* __restrict__ fcw,      // [D, D]
    const float* __restrict__ fcb)      // [D]
{
    const int bd  = blockIdx.x >> 3;
    const int b   = bd >> 6;
    const int d   = bd & (DD - 1);
    const int idx = bd * NN + (blockIdx.x & 7) * 1024 + (threadIdx.x << 2);

    __shared__ float eg[DD];
    if (threadIdx.x < DD) {
        // 8 contiguous partials per (b,j): two dwordx4 loads
        const float4* p = (const float4*)(partial + b * 512 + threadIdx.x * 8);
        const float4 a = p[0], c4 = p[1];
        eg[threadIdx.x] = (a.x + a.y + a.z + a.w) + (c4.x + c4.y + c4.z + c4.w);
    }
    // independent: start the E load before the barrier
    float4 e = *(float4*)(E + idx);
    __syncthreads();

    float acc = 0.f;
#pragma unroll
    for (int j = 0; j < DD; ++j)
        acc = fmaf(eg[j], fcw[d * DD + j], acc);      // eg: LDS broadcast; fcw: s_load
    const float z = acc * (1.0f / (float)KK) + fcb[d];
    const float g = 1.0f + 1.0f / (1.0f + exp2f(-z * LOG2E));   // 1 + sigmoid(z)

    e.x = fmaxf(e.x * g, 0.f);
    e.y = fmaxf(e.y * g, 0.f);
    e.z = fmaxf(e.z * g, 0.f);
    e.w = fmaxf(e.w * g, 0.f);
    *(float4*)(E + idx) = e;
}

extern "C" void kernel_launch(void* const* d_in, const int* in_sizes, int n_in,
                              void* d_out, int out_size, void* d_ws, size_t ws_size,
                              hipStream_t stream) {
    const float* X   = (const float*)d_in[0];   // [B, D, T, H, W]
    const float* cw  = (const float*)d_in[1];   // [K, D]
    const float* sc  = (const float*)d_in[2];   // [K, D]
    const float* fcw = (const float*)d_in[3];   // [D, D]
    const float* fcb = (const float*)d_in[4];   // [D]
    float* out = (float*)d_out;                 // [B, D, T, H, W]

    float* partial = (float*)d_ws;              // [2048], every slot written by K1

    const int grid = BB * DD * (NN / 1024);     // 2048 blocks
    enc_kernel<<<grid, 256, 0, stream>>>(X, cw, sc, out, partial);
    gate_kernel<<<grid, 256, 0, stream>>>(out, partial, fcw, fcb);
}

// Round 6
// 96.663 us; speedup vs baseline: 1.0239x; 1.0239x over previous
//
#include <hip/hip_runtime.h>

// Problem constants: B=4, D=64, K=32, N = T*H*W = 8192
#define BB 4
#define DD 64
#define KK 32
#define NN 8192
#define LOG2E 1.4426950408889634f

// Kernel 1: per (b,d) column chunk of 1024 n's (4/thread, float4).
// E[b,d,n] = sum_k softmax_k(scale*(x-c)^2) * (x-c). Residual form:
// 5 VALU + 1 trans per (elem,k), single wave-uniform prep op per k.
// (R5 lesson: v_pk_fma_f32 does NOT double fp32 rate on CDNA4, and
// polynomial coefficient prep runs on the VALU — residual form is minimal.)
// Softmax args are all <= 0 (scale in [-1,0)) -> single-pass exp2 is safe.
// Block-reduces sum_n E into private partial slot (no atomics, no memset).
__global__ __launch_bounds__(256) void enc_kernel(
    const float* __restrict__ X,        // [B, D, N]
    const float* __restrict__ cw,       // [K, D]
    const float* __restrict__ sc,       // [K, D]
    float* __restrict__ E,              // [B, D, N]  (= d_out, staging)
    float* __restrict__ partial)        // [2048] per-block sums
{
    const int bd   = blockIdx.x >> 3;         // (b,d) pair; 8 chunks each
    const int d    = bd & (DD - 1);
    const int idx  = bd * NN + (blockIdx.x & 7) * 1024 + (threadIdx.x << 2);

    const float4 x = *(const float4*)(X + idx);

    float num0 = 0.f, num1 = 0.f, num2 = 0.f, num3 = 0.f;
    float den0 = 0.f, den1 = 0.f, den2 = 0.f, den3 = 0.f;

#pragma unroll
    for (int k = 0; k < KK; ++k) {
        const float c = cw[k * DD + d];               // wave-uniform -> s_load
        const float s = sc[k * DD + d] * LOG2E;       // exp(x) = exp2(x*log2e)
        const float r0 = x.x - c;
        const float r1 = x.y - c;
        const float r2 = x.z - c;
        const float r3 = x.w - c;
        const float e0 = exp2f(s * r0 * r0);          // native v_exp_f32
        const float e1 = exp2f(s * r1 * r1);
        const float e2 = exp2f(s * r2 * r2);
        const float e3 = exp2f(s * r3 * r3);
        den0 += e0; num0 = fmaf(e0, r0, num0);
        den1 += e1; num1 = fmaf(e1, r1, num1);
        den2 += e2; num2 = fmaf(e2, r2, num2);
        den3 += e3; num3 = fmaf(e3, r3, num3);
    }

    // fast reciprocal (~1 ulp) instead of IEEE div sequence; error << threshold
    float4 out;
    out.x = num0 * __builtin_amdgcn_rcpf(den0);
    out.y = num1 * __builtin_amdgcn_rcpf(den1);
    out.z = num2 * __builtin_amdgcn_rcpf(den2);
    out.w = num3 * __builtin_amdgcn_rcpf(den3);
    *(float4*)(E + idx) = out;

    // block-reduce sum_n E -> private partial slot
    float t = out.x + out.y + out.z + out.w;
#pragma unroll
    for (int off = 32; off > 0; off >>= 1)
        t += __shfl_down(t, off);                     // wave = 64

    __shared__ float smem[4];
    if ((threadIdx.x & 63) == 0) smem[threadIdx.x >> 6] = t;
    __syncthreads();
    if (threadIdx.x == 0)
        partial[blockIdx.x] = smem[0] + smem[1] + smem[2] + smem[3];
}

// Kernel 2: reduce the 512 partials of batch b -> eglob[b,:], compute
// gamma(b,d) redundantly per block (64 FMAs), apply relu(E*(1+gamma)) in
// place. E is L2-resident from kernel 1.
__global__ __launch_bounds__(256) void gate_kernel(
    float* __restrict__ E,              // [B, D, N] in/out (= d_out)
    const float* __restrict__ partial,  // [2048]: partial[(b*64+j)*8 + c]
    const float* __restrict__ fcw,      // [D, D]
    const float* __restrict__ fcb)      // [D]
{
    const int bd  = blockIdx.x >> 3;
    const int b   = bd >> 6;
    const int d   = bd & (DD - 1);
    const int idx = bd * NN + (blockIdx.x & 7) * 1024 + (threadIdx.x << 2);

    __shared__ float eg[DD];
    if (threadIdx.x < DD) {
        // 8 contiguous partials per (b,j): two dwordx4 loads
        const float4* p = (const float4*)(partial + b * 512 + threadIdx.x * 8);
        const float4 a = p[0], c4 = p[1];
        eg[threadIdx.x] = (a.x + a.y + a.z + a.w) + (c4.x + c4.y + c4.z + c4.w);
    }
    // independent: start the E load before the barrier
    float4 e = *(float4*)(E + idx);
    __syncthreads();

    float acc = 0.f;
#pragma unroll
    for (int j = 0; j < DD; ++j)
        acc = fmaf(eg[j], fcw[d * DD + j], acc);      // eg: LDS broadcast; fcw: s_load
    const float z = acc * (1.0f / (float)KK) + fcb[d];
    const float g = 1.0f + 1.0f / (1.0f + exp2f(-z * LOG2E));   // 1 + sigmoid(z)

    e.x = fmaxf(e.x * g, 0.f);
    e.y = fmaxf(e.y * g, 0.f);
    e.z = fmaxf(e.z * g, 0.f);
    e.w = fmaxf(e.w * g, 0.f);
    *(float4*)(E + idx) = e;
}

extern "C" void kernel_launch(void* const* d_in, const int* in_sizes, int n_in,
                              void* d_out, int out_size, void* d_ws, size_t ws_size,
                              hipStream_t stream) {
    const float* X   = (const float*)d_in[0];   // [B, D, T, H, W]
    const float* cw  = (const float*)d_in[1];   // [K, D]
    const float* sc  = (const float*)d_in[2];   // [K, D]
    const float* fcw = (const float*)d_in[3];   // [D, D]
    const float* fcb = (const float*)d_in[4];   // [D]
    float* out = (float*)d_out;                 // [B, D, T, H, W]

    float* partial = (float*)d_ws;              // [2048], every slot written by K1

    const int grid = BB * DD * (NN / 1024);     // 2048 blocks
    enc_kernel<<<grid, 256, 0, stream>>>(X, cw, sc, out, partial);
    gate_kernel<<<grid, 256, 0, stream>>>(out, partial, fcw, fcb);
}